// Round 1
// baseline (1866.903 us; speedup 1.0000x reference)
//
#include <hip/hip_runtime.h>

#define CC 64
#define N_NODES 20000
#define N_EDGES_C 320000
#define RAD_DIM 8
#define HID 64
#define OUTD 256
#define ROW_OUT 512

// ---------------- Kernel 1: per-edge MLP (edge-per-thread, f32 VALU) ----------------
// Weights read via wave-uniform addresses -> scalar loads (shared across 64 edges/wave).
// Hidden vector lives in LDS (stride 65: bank=(t+k)%32, free 2-way) to allow runtime-k
// indexing without scratch. Accumulators (64) in registers, j fully unrolled.
__global__ __launch_bounds__(128) void mlp_kernel(
    const float* __restrict__ radial,
    const float* __restrict__ W0, const float* __restrict__ W1,
    const float* __restrict__ W2, const float* __restrict__ W3,
    float* __restrict__ mix, int e0, int e1)
{
    __shared__ float lds_h[128 * 65];
    float* hme = &lds_h[threadIdx.x * 65];

    int e = e0 + blockIdx.x * 128 + threadIdx.x;
    if (e >= e1) return;

    const float inv_s8 = 0.35355339059327373f;  // 1/sqrt(8)
    const float inv8   = 0.125f;                // 1/sqrt(64)

    float x[8];
    #pragma unroll
    for (int k = 0; k < 8; ++k) x[k] = radial[(size_t)e * 8 + k];

    float acc[64];

    // layer 0: 8 -> 64, silu
    #pragma unroll
    for (int j = 0; j < 64; ++j) acc[j] = 0.f;
    #pragma unroll
    for (int k = 0; k < 8; ++k) {
        float xk = x[k];
        #pragma unroll
        for (int j = 0; j < 64; ++j) acc[j] = fmaf(xk, W0[k * 64 + j], acc[j]);
    }
    #pragma unroll
    for (int j = 0; j < 64; ++j) {
        float t = acc[j] * inv_s8;
        hme[j] = t / (1.f + __expf(-t));
    }

    // layers 1,2: 64 -> 64, silu
    const float* Ws[2] = { W1, W2 };
    #pragma unroll
    for (int L = 0; L < 2; ++L) {
        const float* W = Ws[L];
        #pragma unroll
        for (int j = 0; j < 64; ++j) acc[j] = 0.f;
        #pragma unroll 2
        for (int k = 0; k < 64; ++k) {
            float hk = hme[k];
            #pragma unroll
            for (int j = 0; j < 64; ++j) acc[j] = fmaf(hk, W[k * 64 + j], acc[j]);
        }
        #pragma unroll
        for (int j = 0; j < 64; ++j) {
            float t = acc[j] * inv8;
            hme[j] = t / (1.f + __expf(-t));
        }
    }

    // layer 3: 64 -> 256 (no activation), tiled by 64 outputs
    float* mrow = mix + (size_t)(e - e0) * 256;
    #pragma unroll
    for (int jt = 0; jt < 4; ++jt) {
        #pragma unroll
        for (int j = 0; j < 64; ++j) acc[j] = 0.f;
        #pragma unroll 2
        for (int k = 0; k < 64; ++k) {
            float hk = hme[k];
            #pragma unroll
            for (int j = 0; j < 64; ++j) acc[j] = fmaf(hk, W3[k * 256 + jt * 64 + j], acc[j]);
        }
        #pragma unroll
        for (int j = 0; j < 64; j += 4) {
            float4 v = make_float4(acc[j] * inv8, acc[j+1] * inv8, acc[j+2] * inv8, acc[j+3] * inv8);
            *reinterpret_cast<float4*>(&mrow[jt * 64 + j]) = v;
        }
    }
}

// ---------------- Kernel 2: gather + tensor product + modulate + scatter-add ----------------
// Wave-per-edge, lane = channel c. Coalesced gathers of node_feats[sender],
// coalesced mix reads, 8 device-scope atomicAdds per lane into out[receiver].
__global__ __launch_bounds__(256) void scatter_kernel(
    const float* __restrict__ node_feats,   // [N, 256]: [:,0:64]=s, [:,64:256]=v (C,3)
    const float* __restrict__ vectors,      // [E, 3]
    const int*   __restrict__ senders,
    const int*   __restrict__ receivers,
    const float* __restrict__ mix,          // [chunk, 256]
    float* __restrict__ out,                // [N, 512]
    int e0, int e1)
{
    int wid  = threadIdx.x >> 6;
    int lane = threadIdx.x & 63;
    int e = e0 + blockIdx.x * 4 + wid;
    e = __builtin_amdgcn_readfirstlane(e);   // force scalar address paths
    if (e >= e1) return;

    int snd = senders[e];
    int rcv = receivers[e];

    float r0 = -vectors[(size_t)e * 3 + 0];
    float r1 = -vectors[(size_t)e * 3 + 1];
    float r2 = -vectors[(size_t)e * 3 + 2];
    float inv = 1.0f / sqrtf(r0 * r0 + r1 * r1 + r2 * r2);
    const float s3 = 1.7320508075688772f;    // sqrt(3)
    float Y0 = s3 * r0 * inv, Y1 = s3 * r1 * inv, Y2 = s3 * r2 * inv;

    const float* nf = node_feats + (size_t)snd * 256;
    float s_e = nf[lane];
    float v0  = nf[64 + lane * 3 + 0];
    float v1  = nf[64 + lane * 3 + 1];
    float v2  = nf[64 + lane * 3 + 2];

    const float inv_s3 = 0.5773502691896258f; // 1/sqrt(3)
    float tp_s = (v0 * Y0 + v1 * Y1 + v2 * Y2) * inv_s3;

    const float* mrow = mix + (size_t)(e - e0) * 256;
    float m0 = mrow[lane];
    float m1 = mrow[64 + lane];
    float m2 = mrow[128 + lane];
    float m3 = mrow[192 + lane];

    float* orow = out + (size_t)rcv * 512;
    const float inv_an = 0.0625f;            // 1/AVG_NUM_NEIGHBORS

    atomicAdd(&orow[lane],        s_e  * m0 * inv_an);
    atomicAdd(&orow[64 + lane],   tp_s * m1 * inv_an);

    float mv = m2 * inv_an;
    atomicAdd(&orow[128 + lane * 3 + 0], v0 * mv);
    atomicAdd(&orow[128 + lane * 3 + 1], v1 * mv);
    atomicAdd(&orow[128 + lane * 3 + 2], v2 * mv);

    float ms = s_e * m3 * inv_an;
    atomicAdd(&orow[320 + lane * 3 + 0], Y0 * ms);
    atomicAdd(&orow[320 + lane * 3 + 1], Y1 * ms);
    atomicAdd(&orow[320 + lane * 3 + 2], Y2 * ms);
}

extern "C" void kernel_launch(void* const* d_in, const int* in_sizes, int n_in,
                              void* d_out, int out_size, void* d_ws, size_t ws_size,
                              hipStream_t stream)
{
    const float* node_feats = (const float*)d_in[0];
    const float* vectors    = (const float*)d_in[1];
    const float* radial     = (const float*)d_in[2];
    const int*   senders    = (const int*)d_in[3];
    const int*   receivers  = (const int*)d_in[4];
    const float* W0         = (const float*)d_in[5];
    const float* W1         = (const float*)d_in[6];
    const float* W2         = (const float*)d_in[7];
    const float* W3         = (const float*)d_in[8];
    float* out = (float*)d_out;
    float* mix = (float*)d_ws;

    hipMemsetAsync(d_out, 0, (size_t)out_size * sizeof(float), stream);

    // chunk edges so mix [chunk,256] f32 fits in ws
    size_t per_edge = 256 * sizeof(float);
    long long chunk_ll = (long long)(ws_size / per_edge);
    int chunk = (chunk_ll > N_EDGES_C) ? N_EDGES_C : (int)chunk_ll;
    chunk &= ~127;                 // multiple of 128 (and of 4)
    if (chunk <= 0) chunk = 128;   // degenerate ws; assume ws is at least 128 KB

    for (int s = 0; s < N_EDGES_C; s += chunk) {
        int eend = s + chunk; if (eend > N_EDGES_C) eend = N_EDGES_C;
        int ne = eend - s;
        mlp_kernel<<<dim3((ne + 127) / 128), dim3(128), 0, stream>>>(
            radial, W0, W1, W2, W3, mix, s, eend);
        scatter_kernel<<<dim3((ne + 3) / 4), dim3(256), 0, stream>>>(
            node_feats, vectors, senders, receivers, mix, out, s, eend);
    }
}

// Round 3
// 1773.626 us; speedup vs baseline: 1.0526x; 1.0526x over previous
//
#include <hip/hip_runtime.h>

#define N_NODES_DEF 20000
#define RAD 8
#define HID 64

// ======================= Kernel 1: per-edge radial MLP =======================
// Block = 256 edges (edge-per-thread). Weights staged per-layer into a 16 KB
// LDS buffer, read wave-uniform (broadcast ds_read_b128, 4 weights/instr).
// Hidden vector lives transposed in LDS: sH[k*256 + t] -> lanes consecutive,
// conflict-free, thread-private (no syncs needed for it), k may stay a rolled
// loop (dynamic LDS index is fine; dynamic VGPR index is not).
// LDS = 64KB (sH) + 16KB (sW) = 80KB -> 2 blocks/CU.
__global__ __launch_bounds__(256) void mlp_kernel(
    const float* __restrict__ radial,
    const float* __restrict__ W0g, const float* __restrict__ W1g,
    const float* __restrict__ W2g, const float* __restrict__ W3g,
    float* __restrict__ mix, int e0, int e1)
{
    __shared__ float sH[HID * 256];
    __shared__ float sW[4096];

    const int t = threadIdx.x;
    const int e = e0 + blockIdx.x * 256 + t;
    const bool valid = e < e1;

    float4* sW4 = (float4*)sW;

    // ---- stage W0 (512 floats) ----
    if (t < 128) sW4[t] = ((const float4*)W0g)[t];
    __syncthreads();

    float x[8];
    if (valid) {
        float4 ra = ((const float4*)radial)[(size_t)e * 2 + 0];
        float4 rb = ((const float4*)radial)[(size_t)e * 2 + 1];
        x[0]=ra.x; x[1]=ra.y; x[2]=ra.z; x[3]=ra.w;
        x[4]=rb.x; x[5]=rb.y; x[6]=rb.z; x[7]=rb.w;
    } else {
        #pragma unroll
        for (int k = 0; k < 8; ++k) x[k] = 0.f;
    }

    float acc[64];

    // ---- layer 0: 8 -> 64, silu(acc/sqrt(8)) ----
    #pragma unroll
    for (int j = 0; j < 64; ++j) acc[j] = 0.f;
    #pragma unroll
    for (int k = 0; k < 8; ++k) {
        #pragma unroll
        for (int j = 0; j < 64; ++j) acc[j] = fmaf(x[k], sW[k * 64 + j], acc[j]);
    }
    #pragma unroll
    for (int j = 0; j < 64; ++j) {
        float v = acc[j] * 0.35355339059327373f;
        sH[j * 256 + t] = v / (1.f + __expf(-v));
    }
    __syncthreads();                 // done reading W0
    #pragma unroll
    for (int i = 0; i < 4; ++i) sW4[t + i * 256] = ((const float4*)W1g)[t + i * 256];
    __syncthreads();                 // W1 staged

    // ---- layer 1: 64 -> 64, silu(acc/8) ----
    #pragma unroll
    for (int j = 0; j < 64; ++j) acc[j] = 0.f;
    #pragma unroll 2
    for (int k = 0; k < 64; ++k) {
        float hk = sH[k * 256 + t];
        #pragma unroll
        for (int j = 0; j < 64; ++j) acc[j] = fmaf(hk, sW[k * 64 + j], acc[j]);
    }
    __syncthreads();                 // done reading W1
    #pragma unroll
    for (int i = 0; i < 4; ++i) sW4[t + i * 256] = ((const float4*)W2g)[t + i * 256];
    #pragma unroll
    for (int j = 0; j < 64; ++j) {
        float v = acc[j] * 0.125f;
        sH[j * 256 + t] = v / (1.f + __expf(-v));
    }
    __syncthreads();                 // W2 staged

    // ---- layer 2: 64 -> 64, silu(acc/8) ----
    #pragma unroll
    for (int j = 0; j < 64; ++j) acc[j] = 0.f;
    #pragma unroll 2
    for (int k = 0; k < 64; ++k) {
        float hk = sH[k * 256 + t];
        #pragma unroll
        for (int j = 0; j < 64; ++j) acc[j] = fmaf(hk, sW[k * 64 + j], acc[j]);
    }
    __syncthreads();                 // done reading W2
    #pragma unroll
    for (int j = 0; j < 64; ++j) {
        float v = acc[j] * 0.125f;
        sH[j * 256 + t] = v / (1.f + __expf(-v));
    }

    // ---- layer 3: 64 -> 256 in four 64-wide tiles ----
    float4* mrow = (float4*)(mix + (size_t)(e - e0) * 256);
    #pragma unroll 1
    for (int jt = 0; jt < 4; ++jt) {
        // stage W3 columns [jt*64, jt*64+64)
        #pragma unroll
        for (int i = 0; i < 4; ++i) {
            int m = t + i * 256;                       // 0..1023 (float4 idx)
            sW4[m] = ((const float4*)W3g)[(m >> 4) * 64 + jt * 16 + (m & 15)];
        }
        __syncthreads();

        #pragma unroll
        for (int j = 0; j < 64; ++j) acc[j] = 0.f;
        #pragma unroll 2
        for (int k = 0; k < 64; ++k) {
            float hk = sH[k * 256 + t];
            #pragma unroll
            for (int j = 0; j < 64; ++j) acc[j] = fmaf(hk, sW[k * 64 + j], acc[j]);
        }
        if (valid) {
            #pragma unroll
            for (int j4 = 0; j4 < 16; ++j4)
                mrow[jt * 16 + j4] = make_float4(acc[j4*4+0] * 0.125f, acc[j4*4+1] * 0.125f,
                                                 acc[j4*4+2] * 0.125f, acc[j4*4+3] * 0.125f);
        }
        __syncthreads();             // done reading this W3 tile
    }
}

// ======================= CSR build =======================
__global__ __launch_bounds__(256) void hist_kernel(const int* __restrict__ recv,
                                                   int* __restrict__ cnt, int E)
{
    int i = blockIdx.x * 256 + threadIdx.x;
    if (i < E) atomicAdd(&cnt[recv[i]], 1);
}

__global__ __launch_bounds__(1024) void scan_kernel(const int* __restrict__ cnt,
                                                    int* __restrict__ off,
                                                    int* __restrict__ cursor, int N)
{
    __shared__ int part[1024];
    int t = threadIdx.x;
    int per = (N + 1023) / 1024;
    int base = t * per;
    int s = 0;
    for (int i = 0; i < per; ++i) { int idx = base + i; if (idx < N) s += cnt[idx]; }
    part[t] = s;
    __syncthreads();
    for (int d = 1; d < 1024; d <<= 1) {
        int v = (t >= d) ? part[t - d] : 0;
        __syncthreads();
        part[t] += v;
        __syncthreads();
    }
    int run = (t == 0) ? 0 : part[t - 1];
    for (int i = 0; i < per; ++i) {
        int idx = base + i;
        if (idx < N) { off[idx] = run; cursor[idx] = run; run += cnt[idx]; }
    }
    if (t == 1023) off[N] = part[1023];
}

__global__ __launch_bounds__(256) void fill_kernel(const int* __restrict__ recv,
                                                   int* __restrict__ cursor,
                                                   int* __restrict__ edge_of, int E)
{
    int i = blockIdx.x * 256 + threadIdx.x;
    if (i < E) {
        int p = atomicAdd(&cursor[recv[i]], 1);
        edge_of[p] = i;
    }
}

// ======================= Kernel 2: node-parallel gather =======================
// Wave per node, lane = channel. Reads this node's edge list, recomputes each
// message from mix + node_feats[sender] (L2/L3-resident), accumulates in
// registers, writes the 512-float out row exactly once. Zero atomics.
__global__ __launch_bounds__(256) void gather_kernel(
    const float* __restrict__ node_feats,
    const float* __restrict__ vectors,
    const int*   __restrict__ senders,
    const int*   __restrict__ edge_of,
    const int*   __restrict__ off,
    const float* __restrict__ mix,
    float* __restrict__ out, int N)
{
    int wid  = threadIdx.x >> 6;
    int lane = threadIdx.x & 63;
    int n = blockIdx.x * 4 + wid;
    if (n >= N) return;

    int beg = off[n], end = off[n + 1];

    float a0 = 0.f, a1 = 0.f;
    float b0 = 0.f, b1 = 0.f, b2 = 0.f;
    float c0 = 0.f, c1 = 0.f, c2 = 0.f;

    const float s3  = 1.7320508075688772f;
    const float is3 = 0.5773502691896258f;

    #pragma unroll 2
    for (int i = beg; i < end; ++i) {
        int e   = edge_of[i];
        int snd = senders[e];

        float r0 = -vectors[(size_t)e * 3 + 0];
        float r1 = -vectors[(size_t)e * 3 + 1];
        float r2 = -vectors[(size_t)e * 3 + 2];
        float inv = rsqrtf(r0 * r0 + r1 * r1 + r2 * r2);
        float Y0 = s3 * r0 * inv, Y1 = s3 * r1 * inv, Y2 = s3 * r2 * inv;

        const float* nf = node_feats + (size_t)snd * 256;
        float s_e = nf[lane];
        float v0  = nf[64 + lane * 3 + 0];
        float v1  = nf[64 + lane * 3 + 1];
        float v2  = nf[64 + lane * 3 + 2];

        const float* m = mix + (size_t)e * 256;
        float m0 = m[lane];
        float m1 = m[64 + lane];
        float m2 = m[128 + lane];
        float m3 = m[192 + lane];

        float tp_s = (v0 * Y0 + v1 * Y1 + v2 * Y2) * is3;

        a0 += s_e * m0;
        a1 += tp_s * m1;
        b0 += v0 * m2; b1 += v1 * m2; b2 += v2 * m2;
        float sm = s_e * m3;
        c0 += Y0 * sm; c1 += Y1 * sm; c2 += Y2 * sm;
    }

    float* o = out + (size_t)n * 512;
    const float kk = 0.0625f;
    o[lane]      = a0 * kk;
    o[64 + lane] = a1 * kk;
    o[128 + lane * 3 + 0] = b0 * kk;
    o[128 + lane * 3 + 1] = b1 * kk;
    o[128 + lane * 3 + 2] = b2 * kk;
    o[320 + lane * 3 + 0] = c0 * kk;
    o[320 + lane * 3 + 1] = c1 * kk;
    o[320 + lane * 3 + 2] = c2 * kk;
}

// ======================= Fallback: atomic scatter (small ws) =======================
__global__ __launch_bounds__(256) void scatter_kernel(
    const float* __restrict__ node_feats,
    const float* __restrict__ vectors,
    const int*   __restrict__ senders,
    const int*   __restrict__ receivers,
    const float* __restrict__ mix,
    float* __restrict__ out, int e0, int e1)
{
    int wid  = threadIdx.x >> 6;
    int lane = threadIdx.x & 63;
    int e = e0 + blockIdx.x * 4 + wid;
    if (e >= e1) return;

    int snd = senders[e];
    int rcv = receivers[e];

    float r0 = -vectors[(size_t)e * 3 + 0];
    float r1 = -vectors[(size_t)e * 3 + 1];
    float r2 = -vectors[(size_t)e * 3 + 2];
    float inv = rsqrtf(r0 * r0 + r1 * r1 + r2 * r2);
    float Y0 = 1.7320508075688772f * r0 * inv;
    float Y1 = 1.7320508075688772f * r1 * inv;
    float Y2 = 1.7320508075688772f * r2 * inv;

    const float* nf = node_feats + (size_t)snd * 256;
    float s_e = nf[lane];
    float v0 = nf[64 + lane * 3 + 0];
    float v1 = nf[64 + lane * 3 + 1];
    float v2 = nf[64 + lane * 3 + 2];

    float tp_s = (v0 * Y0 + v1 * Y1 + v2 * Y2) * 0.5773502691896258f;

    const float* m = mix + (size_t)(e - e0) * 256;
    float m0 = m[lane], m1 = m[64 + lane], m2 = m[128 + lane], m3 = m[192 + lane];

    float* orow = out + (size_t)rcv * 512;
    const float kk = 0.0625f;
    atomicAdd(&orow[lane],      s_e  * m0 * kk);
    atomicAdd(&orow[64 + lane], tp_s * m1 * kk);
    float mv = m2 * kk;
    atomicAdd(&orow[128 + lane * 3 + 0], v0 * mv);
    atomicAdd(&orow[128 + lane * 3 + 1], v1 * mv);
    atomicAdd(&orow[128 + lane * 3 + 2], v2 * mv);
    float ms = s_e * m3 * kk;
    atomicAdd(&orow[320 + lane * 3 + 0], Y0 * ms);
    atomicAdd(&orow[320 + lane * 3 + 1], Y1 * ms);
    atomicAdd(&orow[320 + lane * 3 + 2], Y2 * ms);
}

extern "C" void kernel_launch(void* const* d_in, const int* in_sizes, int n_in,
                              void* d_out, int out_size, void* d_ws, size_t ws_size,
                              hipStream_t stream)
{
    const float* node_feats = (const float*)d_in[0];
    const float* vectors    = (const float*)d_in[1];
    const float* radial     = (const float*)d_in[2];
    const int*   senders    = (const int*)d_in[3];
    const int*   receivers  = (const int*)d_in[4];
    const float* W0         = (const float*)d_in[5];
    const float* W1         = (const float*)d_in[6];
    const float* W2         = (const float*)d_in[7];
    const float* W3         = (const float*)d_in[8];
    float* out = (float*)d_out;

    const int E = in_sizes[3];
    const int N = in_sizes[0] / 256;

    size_t mix_bytes = (size_t)E * 256 * sizeof(float);
    size_t mix_al    = (mix_bytes + 255) & ~(size_t)255;
    size_t int_bytes = (size_t)(N + (N + 1) + N + E) * sizeof(int);
    size_t need      = mix_al + int_bytes;

    if (ws_size >= need) {
        // -------- CSR path --------
        float* mix    = (float*)d_ws;
        int* cnt      = (int*)((char*)d_ws + mix_al);
        int* off      = cnt + N;
        int* cursor   = off + (N + 1);
        int* edge_of  = cursor + N;

        hipMemsetAsync(cnt, 0, (size_t)N * sizeof(int), stream);

        mlp_kernel<<<dim3((E + 255) / 256), dim3(256), 0, stream>>>(
            radial, W0, W1, W2, W3, mix, 0, E);

        hist_kernel<<<dim3((E + 255) / 256), dim3(256), 0, stream>>>(receivers, cnt, E);
        scan_kernel<<<dim3(1), dim3(1024), 0, stream>>>(cnt, off, cursor, N);
        fill_kernel<<<dim3((E + 255) / 256), dim3(256), 0, stream>>>(receivers, cursor, edge_of, E);

        gather_kernel<<<dim3((N + 3) / 4), dim3(256), 0, stream>>>(
            node_feats, vectors, senders, edge_of, off, mix, out, N);
    } else {
        // -------- fallback: chunked atomic scatter --------
        hipMemsetAsync(d_out, 0, (size_t)out_size * sizeof(float), stream);
        size_t per_edge = 256 * sizeof(float);
        long long chunk_ll = (long long)(ws_size / per_edge);
        int chunk = (chunk_ll > E) ? E : (int)chunk_ll;
        chunk &= ~255;
        if (chunk <= 0) chunk = 256;
        float* mix = (float*)d_ws;
        for (int s = 0; s < E; s += chunk) {
            int eend = s + chunk; if (eend > E) eend = E;
            int ne = eend - s;
            mlp_kernel<<<dim3((ne + 255) / 256), dim3(256), 0, stream>>>(
                radial, W0, W1, W2, W3, mix, s, eend);
            scatter_kernel<<<dim3((ne + 3) / 4), dim3(256), 0, stream>>>(
                node_feats, vectors, senders, receivers, mix, out, s, eend);
        }
    }
}

// Round 6
// 530.328 us; speedup vs baseline: 3.5203x; 3.3444x over previous
//
#include <hip/hip_runtime.h>

#define RAD 8
#define HID 64

// RNE float -> bf16 (finite inputs)
static __device__ __forceinline__ unsigned short f2bf(float f) {
    unsigned int u = __float_as_uint(f);
    unsigned int r = (u + 0x7fffu + ((u >> 16) & 1u)) >> 16;
    return (unsigned short)r;
}
static __device__ __forceinline__ float bf2f(unsigned short h) {
    return __uint_as_float(((unsigned int)h) << 16);
}

// ======================= Kernel 1: per-edge radial MLP =======================
// Block = 256 edges (edge-per-thread). Weights staged per-layer into 16 KB LDS,
// read as wave-uniform float4 broadcasts (16 ds_read_b128 + 64 FMA per k ->
// FMA-bound). Hidden vector transposed in LDS: sH[k*256+t], lanes consecutive,
// conflict-free, allows rolled k-loop without scratch spill.
// LDS = 64KB (sH) + 16KB (sW) = 80KB -> 2 blocks/CU.
__global__ __launch_bounds__(256) void mlp_kernel(
    const float* __restrict__ radial,   // [e1] rows of 8 floats
    const float* __restrict__ W0g, const float* __restrict__ W1g,
    const float* __restrict__ W2g, const float* __restrict__ W3g,
    unsigned short* __restrict__ mix,   // [e1][256] bf16
    int e1)
{
    __shared__ float  sH[HID * 256];
    __shared__ float4 sW4[1024];

    const int t = threadIdx.x;
    const int e = blockIdx.x * 256 + t;
    const bool valid = e < e1;

    // ---- stage W0 (512 floats = 128 float4) ----
    if (t < 128) sW4[t] = ((const float4*)W0g)[t];
    __syncthreads();

    float x[8];
    if (valid) {
        float4 ra = ((const float4*)radial)[(size_t)e * 2 + 0];
        float4 rb = ((const float4*)radial)[(size_t)e * 2 + 1];
        x[0]=ra.x; x[1]=ra.y; x[2]=ra.z; x[3]=ra.w;
        x[4]=rb.x; x[5]=rb.y; x[6]=rb.z; x[7]=rb.w;
    } else {
        #pragma unroll
        for (int k = 0; k < 8; ++k) x[k] = 0.f;
    }

    float acc[64];

    // ---- layer 0: 8 -> 64, silu(acc/sqrt(8)) ----
    #pragma unroll
    for (int j = 0; j < 64; ++j) acc[j] = 0.f;
    #pragma unroll
    for (int k = 0; k < 8; ++k) {
        #pragma unroll
        for (int jq = 0; jq < 16; ++jq) {
            float4 w = sW4[k * 16 + jq];
            acc[jq*4+0] = fmaf(x[k], w.x, acc[jq*4+0]);
            acc[jq*4+1] = fmaf(x[k], w.y, acc[jq*4+1]);
            acc[jq*4+2] = fmaf(x[k], w.z, acc[jq*4+2]);
            acc[jq*4+3] = fmaf(x[k], w.w, acc[jq*4+3]);
        }
    }
    #pragma unroll
    for (int j = 0; j < 64; ++j) {
        float v = acc[j] * 0.35355339059327373f;
        sH[j * 256 + t] = v / (1.f + __expf(-v));
    }
    __syncthreads();                 // done reading W0
    #pragma unroll
    for (int i = 0; i < 4; ++i) sW4[t + i * 256] = ((const float4*)W1g)[t + i * 256];
    __syncthreads();                 // W1 staged

    // ---- layer 1: 64 -> 64, silu(acc/8) ----
    #pragma unroll
    for (int j = 0; j < 64; ++j) acc[j] = 0.f;
    #pragma unroll 2
    for (int k = 0; k < 64; ++k) {
        float hk = sH[k * 256 + t];
        #pragma unroll
        for (int jq = 0; jq < 16; ++jq) {
            float4 w = sW4[k * 16 + jq];
            acc[jq*4+0] = fmaf(hk, w.x, acc[jq*4+0]);
            acc[jq*4+1] = fmaf(hk, w.y, acc[jq*4+1]);
            acc[jq*4+2] = fmaf(hk, w.z, acc[jq*4+2]);
            acc[jq*4+3] = fmaf(hk, w.w, acc[jq*4+3]);
        }
    }
    __syncthreads();                 // done reading W1
    #pragma unroll
    for (int i = 0; i < 4; ++i) sW4[t + i * 256] = ((const float4*)W2g)[t + i * 256];
    #pragma unroll
    for (int j = 0; j < 64; ++j) {
        float v = acc[j] * 0.125f;
        sH[j * 256 + t] = v / (1.f + __expf(-v));
    }
    __syncthreads();                 // W2 staged

    // ---- layer 2: 64 -> 64, silu(acc/8) ----
    #pragma unroll
    for (int j = 0; j < 64; ++j) acc[j] = 0.f;
    #pragma unroll 2
    for (int k = 0; k < 64; ++k) {
        float hk = sH[k * 256 + t];
        #pragma unroll
        for (int jq = 0; jq < 16; ++jq) {
            float4 w = sW4[k * 16 + jq];
            acc[jq*4+0] = fmaf(hk, w.x, acc[jq*4+0]);
            acc[jq*4+1] = fmaf(hk, w.y, acc[jq*4+1]);
            acc[jq*4+2] = fmaf(hk, w.z, acc[jq*4+2]);
            acc[jq*4+3] = fmaf(hk, w.w, acc[jq*4+3]);
        }
    }
    __syncthreads();                 // done reading W2
    #pragma unroll
    for (int j = 0; j < 64; ++j) {
        float v = acc[j] * 0.125f;
        sH[j * 256 + t] = v / (1.f + __expf(-v));
    }

    // ---- layer 3: 64 -> 256 in four 64-wide tiles, store bf16 ----
    unsigned short* mrow = mix + (size_t)e * 256;
    #pragma unroll 1
    for (int jt = 0; jt < 4; ++jt) {
        // stage W3 cols [jt*64, jt*64+64): row k quad q at sW4[k*16 + q]
        #pragma unroll
        for (int i = 0; i < 4; ++i) {
            int m = t + i * 256;                       // 0..1023
            sW4[m] = ((const float4*)W3g)[(m >> 4) * 64 + jt * 16 + (m & 15)];
        }
        __syncthreads();

        #pragma unroll
        for (int j = 0; j < 64; ++j) acc[j] = 0.f;
        #pragma unroll 2
        for (int k = 0; k < 64; ++k) {
            float hk = sH[k * 256 + t];
            #pragma unroll
            for (int jq = 0; jq < 16; ++jq) {
                float4 w = sW4[k * 16 + jq];
                acc[jq*4+0] = fmaf(hk, w.x, acc[jq*4+0]);
                acc[jq*4+1] = fmaf(hk, w.y, acc[jq*4+1]);
                acc[jq*4+2] = fmaf(hk, w.z, acc[jq*4+2]);
                acc[jq*4+3] = fmaf(hk, w.w, acc[jq*4+3]);
            }
        }
        if (valid) {
            #pragma unroll
            for (int j4 = 0; j4 < 16; ++j4) {
                ushort4 u;
                u.x = f2bf(acc[j4*4+0] * 0.125f);
                u.y = f2bf(acc[j4*4+1] * 0.125f);
                u.z = f2bf(acc[j4*4+2] * 0.125f);
                u.w = f2bf(acc[j4*4+3] * 0.125f);
                *reinterpret_cast<ushort4*>(&mrow[jt * 64 + j4 * 4]) = u;
            }
        }
        __syncthreads();             // done reading this W3 tile
    }
}

// ======================= CSR build =======================
__global__ __launch_bounds__(256) void hist_kernel(const int* __restrict__ recv,
                                                   int* __restrict__ cnt, int E)
{
    int i = blockIdx.x * 256 + threadIdx.x;
    if (i < E) atomicAdd(&cnt[recv[i]], 1);
}

__global__ __launch_bounds__(1024) void scan_kernel(const int* __restrict__ cnt,
                                                    int* __restrict__ off,
                                                    int* __restrict__ cursor, int N)
{
    __shared__ int part[1024];
    int t = threadIdx.x;
    int per = (N + 1023) / 1024;
    int base = t * per;
    int s = 0;
    for (int i = 0; i < per; ++i) { int idx = base + i; if (idx < N) s += cnt[idx]; }
    part[t] = s;
    __syncthreads();
    for (int d = 1; d < 1024; d <<= 1) {
        int v = (t >= d) ? part[t - d] : 0;
        __syncthreads();
        part[t] += v;
        __syncthreads();
    }
    int run = (t == 0) ? 0 : part[t - 1];
    for (int i = 0; i < per; ++i) {
        int idx = base + i;
        if (idx < N) { off[idx] = run; cursor[idx] = run; run += cnt[idx]; }
    }
    if (t == 1023) off[N] = part[1023];
}

__global__ __launch_bounds__(256) void fill_kernel(const int* __restrict__ recv,
                                                   int* __restrict__ cursor,
                                                   int* __restrict__ edge_of, int E)
{
    int i = blockIdx.x * 256 + threadIdx.x;
    if (i < E) {
        int p = atomicAdd(&cursor[recv[i]], 1);
        edge_of[p] = i;
    }
}

// ======================= Kernel 2: node-parallel gather =======================
// Wave per node, lane = channel. Accumulates all messages in registers, writes
// the 512-float out row exactly once. Zero output atomics.
__global__ __launch_bounds__(256) void gather_kernel(
    const float* __restrict__ node_feats,
    const float* __restrict__ vectors,
    const int*   __restrict__ senders,
    const int*   __restrict__ edge_of,
    const int*   __restrict__ off,
    const unsigned short* __restrict__ mix,   // [E][256] bf16
    float* __restrict__ out, int N)
{
    int wid  = threadIdx.x >> 6;
    int lane = threadIdx.x & 63;
    int n = blockIdx.x * 4 + wid;
    if (n >= N) return;

    int beg = off[n], end = off[n + 1];

    float a0 = 0.f, a1 = 0.f;
    float b0 = 0.f, b1 = 0.f, b2 = 0.f;
    float c0 = 0.f, c1 = 0.f, c2 = 0.f;

    const float s3  = 1.7320508075688772f;
    const float is3 = 0.5773502691896258f;

    #pragma unroll 2
    for (int i = beg; i < end; ++i) {
        int e   = edge_of[i];
        int snd = senders[e];

        float r0 = -vectors[(size_t)e * 3 + 0];
        float r1 = -vectors[(size_t)e * 3 + 1];
        float r2 = -vectors[(size_t)e * 3 + 2];
        float inv = rsqrtf(r0 * r0 + r1 * r1 + r2 * r2);
        float Y0 = s3 * r0 * inv, Y1 = s3 * r1 * inv, Y2 = s3 * r2 * inv;

        const float* nf = node_feats + (size_t)snd * 256;
        float s_e = nf[lane];
        float v0  = nf[64 + lane * 3 + 0];
        float v1  = nf[64 + lane * 3 + 1];
        float v2  = nf[64 + lane * 3 + 2];

        const unsigned short* m = mix + (size_t)e * 256;
        float m0 = bf2f(m[lane]);
        float m1 = bf2f(m[64 + lane]);
        float m2 = bf2f(m[128 + lane]);
        float m3 = bf2f(m[192 + lane]);

        float tp_s = (v0 * Y0 + v1 * Y1 + v2 * Y2) * is3;

        a0 += s_e * m0;
        a1 += tp_s * m1;
        b0 += v0 * m2; b1 += v1 * m2; b2 += v2 * m2;
        float sm = s_e * m3;
        c0 += Y0 * sm; c1 += Y1 * sm; c2 += Y2 * sm;
    }

    float* o = out + (size_t)n * 512;
    const float kk = 0.0625f;
    o[lane]      = a0 * kk;
    o[64 + lane] = a1 * kk;
    o[128 + lane * 3 + 0] = b0 * kk;
    o[128 + lane * 3 + 1] = b1 * kk;
    o[128 + lane * 3 + 2] = b2 * kk;
    o[320 + lane * 3 + 0] = c0 * kk;
    o[320 + lane * 3 + 1] = c1 * kk;
    o[320 + lane * 3 + 2] = c2 * kk;
}

// ======================= Fallback: atomic scatter (tiny ws) =======================
__global__ __launch_bounds__(256) void scatter_kernel(
    const float* __restrict__ node_feats,
    const float* __restrict__ vectors,
    const int*   __restrict__ senders,
    const int*   __restrict__ receivers,
    const unsigned short* __restrict__ mix,   // [chunk][256] bf16
    float* __restrict__ out, int e0, int e1)
{
    int wid  = threadIdx.x >> 6;
    int lane = threadIdx.x & 63;
    int e = e0 + blockIdx.x * 4 + wid;
    if (e >= e1) return;

    int snd = senders[e];
    int rcv = receivers[e];

    float r0 = -vectors[(size_t)e * 3 + 0];
    float r1 = -vectors[(size_t)e * 3 + 1];
    float r2 = -vectors[(size_t)e * 3 + 2];
    float inv = rsqrtf(r0 * r0 + r1 * r1 + r2 * r2);
    float Y0 = 1.7320508075688772f * r0 * inv;
    float Y1 = 1.7320508075688772f * r1 * inv;
    float Y2 = 1.7320508075688772f * r2 * inv;

    const float* nf = node_feats + (size_t)snd * 256;
    float s_e = nf[lane];
    float v0 = nf[64 + lane * 3 + 0];
    float v1 = nf[64 + lane * 3 + 1];
    float v2 = nf[64 + lane * 3 + 2];

    float tp_s = (v0 * Y0 + v1 * Y1 + v2 * Y2) * 0.5773502691896258f;

    const unsigned short* m = mix + (size_t)(e - e0) * 256;
    float m0 = bf2f(m[lane]), m1 = bf2f(m[64 + lane]);
    float m2 = bf2f(m[128 + lane]), m3 = bf2f(m[192 + lane]);

    float* orow = out + (size_t)rcv * 512;
    const float kk = 0.0625f;
    atomicAdd(&orow[lane],      s_e  * m0 * kk);
    atomicAdd(&orow[64 + lane], tp_s * m1 * kk);
    float mv = m2 * kk;
    atomicAdd(&orow[128 + lane * 3 + 0], v0 * mv);
    atomicAdd(&orow[128 + lane * 3 + 1], v1 * mv);
    atomicAdd(&orow[128 + lane * 3 + 2], v2 * mv);
    float ms = s_e * m3 * kk;
    atomicAdd(&orow[320 + lane * 3 + 0], Y0 * ms);
    atomicAdd(&orow[320 + lane * 3 + 1], Y1 * ms);
    atomicAdd(&orow[320 + lane * 3 + 2], Y2 * ms);
}

extern "C" void kernel_launch(void* const* d_in, const int* in_sizes, int n_in,
                              void* d_out, int out_size, void* d_ws, size_t ws_size,
                              hipStream_t stream)
{
    const float* node_feats = (const float*)d_in[0];
    const float* vectors    = (const float*)d_in[1];
    const float* radial     = (const float*)d_in[2];
    const int*   senders    = (const int*)d_in[3];
    const int*   receivers  = (const int*)d_in[4];
    const float* W0         = (const float*)d_in[5];
    const float* W1         = (const float*)d_in[6];
    const float* W2         = (const float*)d_in[7];
    const float* W3         = (const float*)d_in[8];
    float* out = (float*)d_out;

    const int E = in_sizes[3];
    const int N = in_sizes[0] / 256;

    size_t mix_bytes = (size_t)E * 256 * sizeof(unsigned short);   // bf16
    size_t mix_al    = (mix_bytes + 255) & ~(size_t)255;
    size_t int_bytes = (size_t)(N + (N + 1) + N + E) * sizeof(int);
    size_t need      = mix_al + int_bytes;

    if (ws_size >= need) {
        // -------- CSR path --------
        unsigned short* mix = (unsigned short*)d_ws;
        int* cnt      = (int*)((char*)d_ws + mix_al);
        int* off      = cnt + N;
        int* cursor   = off + (N + 1);
        int* edge_of  = cursor + N;

        hipMemsetAsync(cnt, 0, (size_t)N * sizeof(int), stream);

        mlp_kernel<<<dim3((E + 255) / 256), dim3(256), 0, stream>>>(
            radial, W0, W1, W2, W3, mix, E);

        hist_kernel<<<dim3((E + 255) / 256), dim3(256), 0, stream>>>(receivers, cnt, E);
        scan_kernel<<<dim3(1), dim3(1024), 0, stream>>>(cnt, off, cursor, N);
        fill_kernel<<<dim3((E + 255) / 256), dim3(256), 0, stream>>>(receivers, cursor, edge_of, E);

        gather_kernel<<<dim3((N + 3) / 4), dim3(256), 0, stream>>>(
            node_feats, vectors, senders, edge_of, off, mix, out, N);
    } else {
        // -------- fallback: chunked atomic scatter --------
        hipMemsetAsync(d_out, 0, (size_t)out_size * sizeof(float), stream);
        size_t per_edge = 256 * sizeof(unsigned short);
        long long chunk_ll = (long long)(ws_size / per_edge);
        int chunk = (chunk_ll > E) ? E : (int)chunk_ll;
        chunk &= ~255;
        if (chunk <= 0) chunk = 256;
        unsigned short* mix = (unsigned short*)d_ws;
        for (int s = 0; s < E; s += chunk) {
            int eend = s + chunk; if (eend > E) eend = E;
            int ne = eend - s;
            // shift radial so kernel's local edge ids [0,ne) read the right rows
            mlp_kernel<<<dim3((ne + 255) / 256), dim3(256), 0, stream>>>(
                radial + (size_t)s * 8, W0, W1, W2, W3, mix, ne);
            scatter_kernel<<<dim3((ne + 3) / 4), dim3(256), 0, stream>>>(
                node_feats, vectors, senders, receivers, mix, out, s, eend);
        }
    }
}

// Round 7
// 232.454 us; speedup vs baseline: 8.0313x; 2.2814x over previous
//
#include <hip/hip_runtime.h>

#define RAD 8
#define HID 64

typedef __attribute__((ext_vector_type(8))) short bf16x8;
typedef __attribute__((ext_vector_type(4))) float f32x4;

// RNE float -> bf16 (finite inputs)
static __device__ __forceinline__ unsigned short f2bf(float f) {
    unsigned int u = __float_as_uint(f);
    unsigned int r = (u + 0x7fffu + ((u >> 16) & 1u)) >> 16;
    return (unsigned short)r;
}
static __device__ __forceinline__ float bf2f(unsigned short h) {
    return __uint_as_float(((unsigned int)h) << 16);
}

// Packed-weight geometry (bf16, fragment-ordered; scales folded in):
//   W0p: [0,2048)      frags nt=0..3             (K=8 zero-padded to 32, *1/sqrt8)
//   W1p: [2048,6144)   frags (nt=0..3, ks=0..1)  (*1/8)
//   W2p: [6144,10240)  frags (nt=0..3, ks=0..1)  (*1/8)
//   W3p: [10240,26624) frags (nt=0..15, ks=0..1) (*1/8)
// Within a frag: elem (lane,j) = W[k][n], k = ks*32 + (lane>>4)*8 + j,
//                n = nt*16 + (lane&15); stored at frag*512 + lane*8 + j.
#define WP_TOTAL 26624

__global__ __launch_bounds__(256) void pack_kernel(
    const float* __restrict__ W0, const float* __restrict__ W1,
    const float* __restrict__ W2, const float* __restrict__ W3,
    unsigned short* __restrict__ Wp)
{
    int o = blockIdx.x * 256 + threadIdx.x;
    if (o >= WP_TOTAL) return;
    float val;
    if (o < 2048) {
        int nt = o >> 9, w = o & 511, lane = w >> 3, j = w & 7;
        int k = (lane >> 4) * 8 + j, n = nt * 16 + (lane & 15);
        val = (k < 8) ? W0[k * 64 + n] * 0.35355339059327373f : 0.f;
    } else if (o < 6144) {
        int oo = o - 2048, fid = oo >> 9, w = oo & 511, lane = w >> 3, j = w & 7;
        int nt = fid >> 1, ks = fid & 1;
        int k = ks * 32 + (lane >> 4) * 8 + j, n = nt * 16 + (lane & 15);
        val = W1[k * 64 + n] * 0.125f;
    } else if (o < 10240) {
        int oo = o - 6144, fid = oo >> 9, w = oo & 511, lane = w >> 3, j = w & 7;
        int nt = fid >> 1, ks = fid & 1;
        int k = ks * 32 + (lane >> 4) * 8 + j, n = nt * 16 + (lane & 15);
        val = W2[k * 64 + n] * 0.125f;
    } else {
        int oo = o - 10240, fid = oo >> 9, w = oo & 511, lane = w >> 3, j = w & 7;
        int nt = fid >> 1, ks = fid & 1;
        int k = ks * 32 + (lane >> 4) * 8 + j, n = nt * 16 + (lane & 15);
        val = W3[k * 256 + n] * 0.125f;
    }
    Wp[o] = f2bf(val);
}

// ======================= MFMA radial MLP =======================
// Block = 256 thr = 4 waves; wave owns 16 edges, fully independent after the
// one weight-staging barrier. mfma_f32_16x16x32_bf16 layouts (m89-verified):
//   A: row=lane&15, k=(lane>>4)*8+j   B: col=lane&15, k=(lane>>4)*8+j
//   D: col=lane&15, row=(lane>>4)*4+r
// Activations H: 16x64 bf16/wave in LDS, XOR-swizzled (idx = er*64 +
// (f ^ ((er&7)<<3))) so stride-128B A-frag ds_read_b128 is conflict-free.
// LDS = 53248 (weights) + 8192 (H) = 60 KB -> 2 blocks/CU.
__global__ __launch_bounds__(256) void mlp_mfma_kernel(
    const float* __restrict__ radial,
    const unsigned short* __restrict__ Wp,
    unsigned short* __restrict__ mix,       // [E][256] bf16
    int E)
{
    __shared__ unsigned short sWp[WP_TOTAL];
    __shared__ unsigned short sH[4][1024];

    const int t = threadIdx.x;
    {   // stage packed weights: 53248 B = 3328 int4 = 13 per thread
        int4* dst = (int4*)sWp;
        const int4* src = (const int4*)Wp;
        #pragma unroll
        for (int i = 0; i < 13; ++i) dst[t + i * 256] = src[t + i * 256];
    }
    __syncthreads();

    const int wv = t >> 6, l = t & 63;
    const int lrow = l & 15;   // A-row (edge) on load; D-col (feature) on store
    const int quad = l >> 4;   // A k-slice; D row-group
    const int e0 = blockIdx.x * 64 + wv * 16;
    if (e0 >= E) return;
    int nval = E - e0; if (nval > 16) nval = 16;

    unsigned short* H = sH[wv];

    // ---- layer 0: A from radial (K=8 padded), B = W0p ----
    bf16x8 a0 = {0, 0, 0, 0, 0, 0, 0, 0};
    if (quad == 0 && lrow < nval) {
        const float* rr = radial + (size_t)(e0 + lrow) * 8;
        #pragma unroll
        for (int j = 0; j < 8; ++j) a0[j] = (short)f2bf(rr[j]);
    }
    {
        f32x4 c[4];
        #pragma unroll
        for (int nt = 0; nt < 4; ++nt) {
            bf16x8 b = *(const bf16x8*)(sWp + nt * 512 + l * 8);
            f32x4 z = {0.f, 0.f, 0.f, 0.f};
            c[nt] = __builtin_amdgcn_mfma_f32_16x16x32_bf16(a0, b, z, 0, 0, 0);
        }
        #pragma unroll
        for (int nt = 0; nt < 4; ++nt) {
            #pragma unroll
            for (int r = 0; r < 4; ++r) {
                float v = c[nt][r];
                float h = v / (1.f + __expf(-v));
                int er = quad * 4 + r;
                int f  = nt * 16 + lrow;
                H[er * 64 + (f ^ ((er & 7) << 3))] = f2bf(h);
            }
        }
    }

    // ---- layers 1,2: 64 -> 64, silu ----
    #pragma unroll 1
    for (int L = 0; L < 2; ++L) {
        const unsigned short* WL = sWp + 2048 + L * 4096;
        bf16x8 a[2];
        #pragma unroll
        for (int ks = 0; ks < 2; ++ks)
            a[ks] = *(const bf16x8*)(H + lrow * 64 + ((ks * 32 + quad * 8) ^ ((lrow & 7) << 3)));
        f32x4 c[4];
        #pragma unroll
        for (int nt = 0; nt < 4; ++nt) { f32x4 z = {0.f,0.f,0.f,0.f}; c[nt] = z; }
        #pragma unroll
        for (int ks = 0; ks < 2; ++ks) {
            #pragma unroll
            for (int nt = 0; nt < 4; ++nt) {
                bf16x8 b = *(const bf16x8*)(WL + (nt * 2 + ks) * 512 + l * 8);
                c[nt] = __builtin_amdgcn_mfma_f32_16x16x32_bf16(a[ks], b, c[nt], 0, 0, 0);
            }
        }
        #pragma unroll
        for (int nt = 0; nt < 4; ++nt) {
            #pragma unroll
            for (int r = 0; r < 4; ++r) {
                float v = c[nt][r];
                float h = v / (1.f + __expf(-v));
                int er = quad * 4 + r;
                int f  = nt * 16 + lrow;
                H[er * 64 + (f ^ ((er & 7) << 3))] = f2bf(h);
            }
        }
    }

    // ---- layer 3: 64 -> 256, no activation, store bf16 mix ----
    {
        const unsigned short* WL = sWp + 10240;
        bf16x8 a[2];
        #pragma unroll
        for (int ks = 0; ks < 2; ++ks)
            a[ks] = *(const bf16x8*)(H + lrow * 64 + ((ks * 32 + quad * 8) ^ ((lrow & 7) << 3)));
        #pragma unroll 1
        for (int g = 0; g < 4; ++g) {
            f32x4 c[4];
            #pragma unroll
            for (int np = 0; np < 4; ++np) { f32x4 z = {0.f,0.f,0.f,0.f}; c[np] = z; }
            #pragma unroll
            for (int ks = 0; ks < 2; ++ks) {
                #pragma unroll
                for (int np = 0; np < 4; ++np) {
                    int nt = g * 4 + np;
                    bf16x8 b = *(const bf16x8*)(WL + (nt * 2 + ks) * 512 + l * 8);
                    c[np] = __builtin_amdgcn_mfma_f32_16x16x32_bf16(a[ks], b, c[np], 0, 0, 0);
                }
            }
            #pragma unroll
            for (int np = 0; np < 4; ++np) {
                #pragma unroll
                for (int r = 0; r < 4; ++r) {
                    int er = quad * 4 + r;
                    if (er < nval) {
                        int f = (g * 4 + np) * 16 + lrow;
                        mix[(size_t)(e0 + er) * 256 + f] = f2bf(c[np][r]);
                    }
                }
            }
        }
    }
}

// ======================= CSR build =======================
__global__ __launch_bounds__(256) void hist_kernel(const int* __restrict__ recv,
                                                   int* __restrict__ cnt, int E)
{
    int i = blockIdx.x * 256 + threadIdx.x;
    if (i < E) atomicAdd(&cnt[recv[i]], 1);
}

__global__ __launch_bounds__(1024) void scan_kernel(const int* __restrict__ cnt,
                                                    int* __restrict__ off,
                                                    int* __restrict__ cursor, int N)
{
    __shared__ int part[1024];
    int t = threadIdx.x;
    int per = (N + 1023) / 1024;
    int base = t * per;
    int s = 0;
    for (int i = 0; i < per; ++i) { int idx = base + i; if (idx < N) s += cnt[idx]; }
    part[t] = s;
    __syncthreads();
    for (int d = 1; d < 1024; d <<= 1) {
        int v = (t >= d) ? part[t - d] : 0;
        __syncthreads();
        part[t] += v;
        __syncthreads();
    }
    int run = (t == 0) ? 0 : part[t - 1];
    for (int i = 0; i < per; ++i) {
        int idx = base + i;
        if (idx < N) { off[idx] = run; cursor[idx] = run; run += cnt[idx]; }
    }
    if (t == 1023) off[N] = part[1023];
}

__global__ __launch_bounds__(256) void fill_kernel(const int* __restrict__ recv,
                                                   int* __restrict__ cursor,
                                                   int* __restrict__ edge_of, int E)
{
    int i = blockIdx.x * 256 + threadIdx.x;
    if (i < E) {
        int p = atomicAdd(&cursor[recv[i]], 1);
        edge_of[p] = i;
    }
}

// ======================= node-parallel gather =======================
__global__ __launch_bounds__(256) void gather_kernel(
    const float* __restrict__ node_feats,
    const float* __restrict__ vectors,
    const int*   __restrict__ senders,
    const int*   __restrict__ edge_of,
    const int*   __restrict__ off,
    const unsigned short* __restrict__ mix,   // [E][256] bf16
    float* __restrict__ out, int N)
{
    int wid  = threadIdx.x >> 6;
    int lane = threadIdx.x & 63;
    int n = blockIdx.x * 4 + wid;
    if (n >= N) return;

    int beg = off[n], end = off[n + 1];

    float a0 = 0.f, a1 = 0.f;
    float b0 = 0.f, b1 = 0.f, b2 = 0.f;
    float c0 = 0.f, c1 = 0.f, c2 = 0.f;

    const float s3  = 1.7320508075688772f;
    const float is3 = 0.5773502691896258f;

    #pragma unroll 2
    for (int i = beg; i < end; ++i) {
        int e   = edge_of[i];
        int snd = senders[e];

        float r0 = -vectors[(size_t)e * 3 + 0];
        float r1 = -vectors[(size_t)e * 3 + 1];
        float r2 = -vectors[(size_t)e * 3 + 2];
        float inv = rsqrtf(r0 * r0 + r1 * r1 + r2 * r2);
        float Y0 = s3 * r0 * inv, Y1 = s3 * r1 * inv, Y2 = s3 * r2 * inv;

        const float* nf = node_feats + (size_t)snd * 256;
        float s_e = nf[lane];
        float v0  = nf[64 + lane * 3 + 0];
        float v1  = nf[64 + lane * 3 + 1];
        float v2  = nf[64 + lane * 3 + 2];

        const unsigned short* m = mix + (size_t)e * 256;
        float m0 = bf2f(m[lane]);
        float m1 = bf2f(m[64 + lane]);
        float m2 = bf2f(m[128 + lane]);
        float m3 = bf2f(m[192 + lane]);

        float tp_s = (v0 * Y0 + v1 * Y1 + v2 * Y2) * is3;

        a0 += s_e * m0;
        a1 += tp_s * m1;
        b0 += v0 * m2; b1 += v1 * m2; b2 += v2 * m2;
        float sm = s_e * m3;
        c0 += Y0 * sm; c1 += Y1 * sm; c2 += Y2 * sm;
    }

    float* o = out + (size_t)n * 512;
    const float kk = 0.0625f;
    o[lane]      = a0 * kk;
    o[64 + lane] = a1 * kk;
    o[128 + lane * 3 + 0] = b0 * kk;
    o[128 + lane * 3 + 1] = b1 * kk;
    o[128 + lane * 3 + 2] = b2 * kk;
    o[320 + lane * 3 + 0] = c0 * kk;
    o[320 + lane * 3 + 1] = c1 * kk;
    o[320 + lane * 3 + 2] = c2 * kk;
}

// ======================= Fallback path (tiny ws): VALU MLP + atomic scatter ==========
__global__ __launch_bounds__(256) void mlp_kernel(
    const float* __restrict__ radial,
    const float* __restrict__ W0g, const float* __restrict__ W1g,
    const float* __restrict__ W2g, const float* __restrict__ W3g,
    unsigned short* __restrict__ mix, int e1)
{
    __shared__ float  sHf[HID * 256];
    __shared__ float4 sW4[1024];

    const int t = threadIdx.x;
    const int e = blockIdx.x * 256 + t;
    const bool valid = e < e1;

    if (t < 128) sW4[t] = ((const float4*)W0g)[t];
    __syncthreads();

    float x[8];
    if (valid) {
        float4 ra = ((const float4*)radial)[(size_t)e * 2 + 0];
        float4 rb = ((const float4*)radial)[(size_t)e * 2 + 1];
        x[0]=ra.x; x[1]=ra.y; x[2]=ra.z; x[3]=ra.w;
        x[4]=rb.x; x[5]=rb.y; x[6]=rb.z; x[7]=rb.w;
    } else {
        #pragma unroll
        for (int k = 0; k < 8; ++k) x[k] = 0.f;
    }

    float acc[64];
    #pragma unroll
    for (int j = 0; j < 64; ++j) acc[j] = 0.f;
    #pragma unroll
    for (int k = 0; k < 8; ++k) {
        #pragma unroll
        for (int jq = 0; jq < 16; ++jq) {
            float4 w = sW4[k * 16 + jq];
            acc[jq*4+0] = fmaf(x[k], w.x, acc[jq*4+0]);
            acc[jq*4+1] = fmaf(x[k], w.y, acc[jq*4+1]);
            acc[jq*4+2] = fmaf(x[k], w.z, acc[jq*4+2]);
            acc[jq*4+3] = fmaf(x[k], w.w, acc[jq*4+3]);
        }
    }
    #pragma unroll
    for (int j = 0; j < 64; ++j) {
        float v = acc[j] * 0.35355339059327373f;
        sHf[j * 256 + t] = v / (1.f + __expf(-v));
    }
    __syncthreads();
    #pragma unroll
    for (int i = 0; i < 4; ++i) sW4[t + i * 256] = ((const float4*)W1g)[t + i * 256];
    __syncthreads();

    #pragma unroll
    for (int j = 0; j < 64; ++j) acc[j] = 0.f;
    #pragma unroll 2
    for (int k = 0; k < 64; ++k) {
        float hk = sHf[k * 256 + t];
        #pragma unroll
        for (int jq = 0; jq < 16; ++jq) {
            float4 w = sW4[k * 16 + jq];
            acc[jq*4+0] = fmaf(hk, w.x, acc[jq*4+0]);
            acc[jq*4+1] = fmaf(hk, w.y, acc[jq*4+1]);
            acc[jq*4+2] = fmaf(hk, w.z, acc[jq*4+2]);
            acc[jq*4+3] = fmaf(hk, w.w, acc[jq*4+3]);
        }
    }
    __syncthreads();
    #pragma unroll
    for (int i = 0; i < 4; ++i) sW4[t + i * 256] = ((const float4*)W2g)[t + i * 256];
    #pragma unroll
    for (int j = 0; j < 64; ++j) {
        float v = acc[j] * 0.125f;
        sHf[j * 256 + t] = v / (1.f + __expf(-v));
    }
    __syncthreads();

    #pragma unroll
    for (int j = 0; j < 64; ++j) acc[j] = 0.f;
    #pragma unroll 2
    for (int k = 0; k < 64; ++k) {
        float hk = sHf[k * 256 + t];
        #pragma unroll
        for (int jq = 0; jq < 16; ++jq) {
            float4 w = sW4[k * 16 + jq];
            acc[jq*4+0] = fmaf(hk, w.x, acc[jq*4+0]);
            acc[jq*4+1] = fmaf(hk, w.y, acc[jq*4+1]);
            acc[jq*4+2] = fmaf(hk, w.z, acc[jq*4+2]);
            acc[jq*4+3] = fmaf(hk, w.w, acc[jq*4+3]);
        }
    }
    __syncthreads();
    #pragma unroll
    for (int j = 0; j < 64; ++j) {
        float v = acc[j] * 0.125f;
        sHf[j * 256 + t] = v / (1.f + __expf(-v));
    }

    unsigned short* mrow = mix + (size_t)e * 256;
    #pragma unroll 1
    for (int jt = 0; jt < 4; ++jt) {
        #pragma unroll
        for (int i = 0; i < 4; ++i) {
            int m = t + i * 256;
            sW4[m] = ((const float4*)W3g)[(m >> 4) * 64 + jt * 16 + (m & 15)];
        }
        __syncthreads();

        #pragma unroll
        for (int j = 0; j < 64; ++j) acc[j] = 0.f;
        #pragma unroll 2
        for (int k = 0; k < 64; ++k) {
            float hk = sHf[k * 256 + t];
            #pragma unroll
            for (int jq = 0; jq < 16; ++jq) {
                float4 w = sW4[k * 16 + jq];
                acc[jq*4+0] = fmaf(hk, w.x, acc[jq*4+0]);
                acc[jq*4+1] = fmaf(hk, w.y, acc[jq*4+1]);
                acc[jq*4+2] = fmaf(hk, w.z, acc[jq*4+2]);
                acc[jq*4+3] = fmaf(hk, w.w, acc[jq*4+3]);
            }
        }
        if (valid) {
            #pragma unroll
            for (int j4 = 0; j4 < 16; ++j4) {
                ushort4 u;
                u.x = f2bf(acc[j4*4+0] * 0.125f);
                u.y = f2bf(acc[j4*4+1] * 0.125f);
                u.z = f2bf(acc[j4*4+2] * 0.125f);
                u.w = f2bf(acc[j4*4+3] * 0.125f);
                *reinterpret_cast<ushort4*>(&mrow[jt * 64 + j4 * 4]) = u;
            }
        }
        __syncthreads();
    }
}

__global__ __launch_bounds__(256) void scatter_kernel(
    const float* __restrict__ node_feats,
    const float* __restrict__ vectors,
    const int*   __restrict__ senders,
    const int*   __restrict__ receivers,
    const unsigned short* __restrict__ mix,
    float* __restrict__ out, int e0, int e1)
{
    int wid  = threadIdx.x >> 6;
    int lane = threadIdx.x & 63;
    int e = e0 + blockIdx.x * 4 + wid;
    if (e >= e1) return;

    int snd = senders[e];
    int rcv = receivers[e];

    float r0 = -vectors[(size_t)e * 3 + 0];
    float r1 = -vectors[(size_t)e * 3 + 1];
    float r2 = -vectors[(size_t)e * 3 + 2];
    float inv = rsqrtf(r0 * r0 + r1 * r1 + r2 * r2);
    float Y0 = 1.7320508075688772f * r0 * inv;
    float Y1 = 1.7320508075688772f * r1 * inv;
    float Y2 = 1.7320508075688772f * r2 * inv;

    const float* nf = node_feats + (size_t)snd * 256;
    float s_e = nf[lane];
    float v0 = nf[64 + lane * 3 + 0];
    float v1 = nf[64 + lane * 3 + 1];
    float v2 = nf[64 + lane * 3 + 2];

    float tp_s = (v0 * Y0 + v1 * Y1 + v2 * Y2) * 0.5773502691896258f;

    const unsigned short* m = mix + (size_t)(e - e0) * 256;
    float m0 = bf2f(m[lane]), m1 = bf2f(m[64 + lane]);
    float m2 = bf2f(m[128 + lane]), m3 = bf2f(m[192 + lane]);

    float* orow = out + (size_t)rcv * 512;
    const float kk = 0.0625f;
    atomicAdd(&orow[lane],      s_e  * m0 * kk);
    atomicAdd(&orow[64 + lane], tp_s * m1 * kk);
    float mv = m2 * kk;
    atomicAdd(&orow[128 + lane * 3 + 0], v0 * mv);
    atomicAdd(&orow[128 + lane * 3 + 1], v1 * mv);
    atomicAdd(&orow[128 + lane * 3 + 2], v2 * mv);
    float ms = s_e * m3 * kk;
    atomicAdd(&orow[320 + lane * 3 + 0], Y0 * ms);
    atomicAdd(&orow[320 + lane * 3 + 1], Y1 * ms);
    atomicAdd(&orow[320 + lane * 3 + 2], Y2 * ms);
}

extern "C" void kernel_launch(void* const* d_in, const int* in_sizes, int n_in,
                              void* d_out, int out_size, void* d_ws, size_t ws_size,
                              hipStream_t stream)
{
    const float* node_feats = (const float*)d_in[0];
    const float* vectors    = (const float*)d_in[1];
    const float* radial     = (const float*)d_in[2];
    const int*   senders    = (const int*)d_in[3];
    const int*   receivers  = (const int*)d_in[4];
    const float* W0         = (const float*)d_in[5];
    const float* W1         = (const float*)d_in[6];
    const float* W2         = (const float*)d_in[7];
    const float* W3         = (const float*)d_in[8];
    float* out = (float*)d_out;

    const int E = in_sizes[3];
    const int N = in_sizes[0] / 256;

    size_t mix_bytes = (size_t)E * 256 * sizeof(unsigned short);   // bf16
    size_t mix_al    = (mix_bytes + 255) & ~(size_t)255;
    size_t int_bytes = (size_t)(N + (N + 1) + N + E) * sizeof(int);
    size_t int_al    = (int_bytes + 255) & ~(size_t)255;
    size_t wp_bytes  = (size_t)WP_TOTAL * sizeof(unsigned short);
    size_t need      = mix_al + int_al + wp_bytes;

    if (ws_size >= need) {
        // -------- CSR + MFMA path --------
        unsigned short* mix = (unsigned short*)d_ws;
        int* cnt      = (int*)((char*)d_ws + mix_al);
        int* off      = cnt + N;
        int* cursor   = off + (N + 1);
        int* edge_of  = cursor + N;
        unsigned short* Wp = (unsigned short*)((char*)d_ws + mix_al + int_al);

        hipMemsetAsync(cnt, 0, (size_t)N * sizeof(int), stream);

        pack_kernel<<<dim3((WP_TOTAL + 255) / 256), dim3(256), 0, stream>>>(
            W0, W1, W2, W3, Wp);
        mlp_mfma_kernel<<<dim3((E + 63) / 64), dim3(256), 0, stream>>>(
            radial, Wp, mix, E);

        hist_kernel<<<dim3((E + 255) / 256), dim3(256), 0, stream>>>(receivers, cnt, E);
        scan_kernel<<<dim3(1), dim3(1024), 0, stream>>>(cnt, off, cursor, N);
        fill_kernel<<<dim3((E + 255) / 256), dim3(256), 0, stream>>>(receivers, cursor, edge_of, E);

        gather_kernel<<<dim3((N + 3) / 4), dim3(256), 0, stream>>>(
            node_feats, vectors, senders, edge_of, off, mix, out, N);
    } else {
        // -------- fallback: chunked VALU MLP + atomic scatter --------
        hipMemsetAsync(d_out, 0, (size_t)out_size * sizeof(float), stream);
        size_t per_edge = 256 * sizeof(unsigned short);
        long long chunk_ll = (long long)(ws_size / per_edge);
        int chunk = (chunk_ll > E) ? E : (int)chunk_ll;
        chunk &= ~255;
        if (chunk <= 0) chunk = 256;
        unsigned short* mix = (unsigned short*)d_ws;
        for (int s = 0; s < E; s += chunk) {
            int eend = s + chunk; if (eend > E) eend = E;
            int ne = eend - s;
            mlp_kernel<<<dim3((ne + 255) / 256), dim3(256), 0, stream>>>(
                radial + (size_t)s * 8, W0, W1, W2, W3, mix, ne);
            scatter_kernel<<<dim3((ne + 3) / 4), dim3(256), 0, stream>>>(
                node_feats, vectors, senders, receivers, mix, out, s, eend);
        }
    }
}